// Round 5
// baseline (1386.652 us; speedup 1.0000x reference)
//
#include <hip/hip_runtime.h>
#include <stdint.h>
#include <stddef.h>

// ---------------- problem constants ----------------
#define BATCH 8
#define NPT   2048
#define NB    (BATCH*NPT)            // 16384
#define CAP   128                    // max sparse entries per row/col
#define ITERS 100
#define TPB   1024
#define NWAVE (TPB/64)
#define NSLICE 4                     // blocks per batch in iterate
#define C50      1.9287498479639178e-22f   // expf(-50.f) == clamp floor of K
#define MUV      (1.0f/2048.0f)
#define EPS_DIVF 1e-8f

// ---------------- workspace layout (bytes), 16B-aligned ----------------
#define OFF_GMAX 0u                                   // gmax[dir][b*32+g]
#define OFF_BAR  4096u                                // 8 batches x 128 B barrier state
#define OFF_CNT  8192u                                // cnt[dir][b][n], 128 KB
#define OFF_PERM (OFF_CNT + (size_t)2*NB*4)           // u16 perm[dir][b][p], 64 KB
#define OFF_PART (OFF_PERM + (size_t)2*NB*2)          // f32 part[b][parity][s][NPT], 512 KB
#define OFF_SPTS (OFF_PART + (size_t)BATCH*2*NSLICE*NPT*4)
#define OFF_TPTS (OFF_SPTS + (size_t)NB*16)
#define OFF_U    (OFF_TPTS + (size_t)NB*16)
#define OFF_V    (OFF_U + (size_t)NB*4)
#define OFF_ROWE (OFF_V + (size_t)NB*4)               // ELL-T4 slab (sorted rows), 8 MB
#define OFF_COLE (OFF_ROWE + (size_t)NB*CAP*4)        // 8 MB
// total ~17.3 MB

// Pack (K - C50): keep 12 mantissa bits (round-to-nearest), low 11 bits = column index.
__device__ __forceinline__ uint32_t pack_entry(float kv, int idx) {
    uint32_t bb = __float_as_uint(kv);
    bb = (bb + 0x400u) & 0xFFFFF800u;
    return bb | (uint32_t)idx;
}

// ELL-T4 address of entry `ofs` of sorted-row `p` within a batch slab (dword units)
__device__ __forceinline__ size_t ellt4_addr(int ofs, int p) {
    return (size_t)(ofs >> 2) * (NPT*4) + (size_t)p * 4 + (ofs & 3);
}

// 4-block sense-reversing barrier (agent scope; __syncthreads drains each wave's vmcnt
// before thread 0 signals, and data loads after it use sc-coherent atomics).
__device__ __forceinline__ void group_barrier(uint32_t* bcnt, uint32_t* bepo, int nblk)
{
    __syncthreads();
    if (threadIdx.x == 0) {
        __threadfence();
        uint32_t e = __hip_atomic_load(bepo, __ATOMIC_RELAXED, __HIP_MEMORY_SCOPE_AGENT);
        uint32_t a = __hip_atomic_fetch_add(bcnt, 1u, __ATOMIC_ACQ_REL, __HIP_MEMORY_SCOPE_AGENT) + 1u;
        if (a == (uint32_t)nblk) {
            __hip_atomic_store(bcnt, 0u, __ATOMIC_RELAXED, __HIP_MEMORY_SCOPE_AGENT);
            __hip_atomic_fetch_add(bepo, 1u, __ATOMIC_RELEASE, __HIP_MEMORY_SCOPE_AGENT);
        } else {
            while (__hip_atomic_load(bepo, __ATOMIC_RELAXED, __HIP_MEMORY_SCOPE_AGENT) == e) {
                __builtin_amdgcn_s_sleep(1);
            }
        }
        __threadfence();
    }
    __syncthreads();
}

// ========== kernel A: stage float4 points + per-row/col entry counts ==========
extern "C" __global__ __launch_bounds__(TPB, 2)
void emd_count_56831007261025(const float* __restrict__ src,
                              const float* __restrict__ tgt,
                              uint8_t* __restrict__ wsb,
                              float* __restrict__ out)
{
    __shared__ float4 opts[NPT];

    uint32_t* cnt   = (uint32_t*)(wsb + OFF_CNT);
    float4*   gspts = (float4*)  (wsb + OFF_SPTS);
    float4*   gtpts = (float4*)  (wsb + OFF_TPTS);

    const int tid  = threadIdx.x;
    const int lane = tid & 63;
    const int wid  = tid >> 6;
    const int b    = blockIdx.x >> 5;
    const int g    = blockIdx.x & 31;
    const size_t base = (size_t)b * NPT;

    if (blockIdx.x == 0 && tid == 0) *out = 0.0f;
    if (blockIdx.x == 0 && tid < 256) ((uint32_t*)(wsb + OFF_BAR))[tid] = 0u;  // barrier init

    if (tid < 64) {
        size_t gi = base + g*64 + tid;
        gspts[gi] = make_float4(src[3*gi], src[3*gi+1], src[3*gi+2], 0.0f);
        gtpts[gi] = make_float4(tgt[3*gi], tgt[3*gi+1], tgt[3*gi+2], 0.0f);
    }

    for (int pass = 0; pass < 2; ++pass) {
        const float* mineRaw  = pass ? tgt : src;
        const float* cloudRaw = pass ? src : tgt;

        __syncthreads();
        for (int i = tid; i < NPT; i += TPB) {
            size_t gi = base + i;
            opts[i] = make_float4(cloudRaw[3*gi], cloudRaw[3*gi+1], cloudRaw[3*gi+2], 0.0f);
        }
        __syncthreads();

        for (int r = 0; r < 4; ++r) {
            int n = g*64 + wid*4 + r;
            size_t gi = base + n;
            float4 sp = make_float4(mineRaw[3*gi], mineRaw[3*gi+1], mineRaw[3*gi+2], 0.0f);
            uint32_t c = 0;
            for (int mb = 0; mb < NPT; mb += 64) {
                float4 tp = opts[mb + lane];
                float dx = sp.x - tp.x, dy = sp.y - tp.y, dz = sp.z - tp.z;
                float d2 = dx*dx + dy*dy + dz*dz;
                c += (uint32_t)__popcll(__ballot(d2 < 0.25f));
            }
            if (lane == 0) cnt[(size_t)pass*NB + gi] = (c < CAP) ? c : CAP;
        }
    }
}

// ========== kernel B: counting-sort rows by count, per (dir, batch) ==========
extern "C" __global__ __launch_bounds__(256, 4)
void emd_sort_56831007261025(uint8_t* __restrict__ wsb)
{
    __shared__ uint32_t hist[CAP+2];
    __shared__ uint32_t bofs[CAP+2];
    __shared__ uint16_t permL[NPT];

    const int tid = threadIdx.x;
    const int dir = blockIdx.x >> 3;
    const int b   = blockIdx.x & 7;

    const uint32_t* cnt  = (const uint32_t*)(wsb + OFF_CNT) + (size_t)dir*NB + (size_t)b*NPT;
    uint16_t*       perm = (uint16_t*)(wsb + OFF_PERM) + (size_t)dir*NB + (size_t)b*NPT;
    uint32_t*       gmax = (uint32_t*)(wsb + OFF_GMAX) + (size_t)dir*256 + (size_t)b*32;

    for (int i = tid; i < CAP+2; i += 256) hist[i] = 0;
    __syncthreads();
    for (int n = tid; n < NPT; n += 256) atomicAdd(&hist[cnt[n]], 1u);
    __syncthreads();
    if (tid == 0) {
        uint32_t run = 0;
        for (int i = 0; i < CAP+2; ++i) { bofs[i] = run; run += hist[i]; }
    }
    __syncthreads();
    for (int n = tid; n < NPT; n += 256) {
        uint32_t p = atomicAdd(&bofs[cnt[n]], 1u);
        permL[p] = (uint16_t)n;
    }
    __syncthreads();
    for (int p = tid; p < NPT; p += 256) perm[p] = permL[p];
    if (tid < 32) gmax[tid] = cnt[permL[tid*64 + 63]];   // sorted ascending -> group max
}

// ========== kernel C: build ELL-T4 slabs at sorted row positions ==========
extern "C" __global__ __launch_bounds__(TPB, 2)
void emd_build_56831007261025(uint8_t* __restrict__ wsb)
{
    __shared__ float4   opts[NPT];
    __shared__ uint16_t rows[64];

    const float4* gspts = (const float4*)(wsb + OFF_SPTS);
    const float4* gtpts = (const float4*)(wsb + OFF_TPTS);
    uint32_t*     rowE  = (uint32_t*)(wsb + OFF_ROWE);
    uint32_t*     colE  = (uint32_t*)(wsb + OFF_COLE);

    const int tid  = threadIdx.x;
    const int lane = tid & 63;
    const int wid  = tid >> 6;
    const int b    = blockIdx.x >> 5;
    const int g    = blockIdx.x & 31;
    const size_t base  = (size_t)b * NPT;
    const size_t ebase = (size_t)b * NPT * CAP;

    // zero-fill this block's sorted-row slice in both slabs (padding entries == 0)
    for (int idx = tid; idx < 32*256; idx += TPB) {
        int j4 = idx >> 8, t = idx & 255;
        size_t a = ebase + (size_t)j4*(NPT*4) + (size_t)g*256 + t;
        rowE[a] = 0u;
        colE[a] = 0u;
    }

    for (int pass = 0; pass < 2; ++pass) {
        const float4* mine  = pass ? gtpts : gspts;
        const float4* cloud = pass ? gspts : gtpts;
        uint32_t*     E     = pass ? colE : rowE;
        const uint16_t* perm = (const uint16_t*)(wsb + OFF_PERM) + (size_t)pass*NB + base;

        __syncthreads();
        for (int i = tid; i < NPT; i += TPB) opts[i] = cloud[base + i];
        if (tid < 64) rows[tid] = perm[g*64 + tid];
        __syncthreads();

        for (int r = 0; r < 4; ++r) {
            int psort = g*64 + wid*4 + r;              // sorted position (slab row)
            int n     = rows[wid*4 + r];               // original row
            float4 sp = mine[base + n];
            uint32_t c = 0;
            for (int mb = 0; mb < NPT; mb += 64) {
                int m = mb + lane;
                float4 tp = opts[m];
                float dx = sp.x - tp.x, dy = sp.y - tp.y, dz = sp.z - tp.z;
                float d2 = dx*dx + dy*dy + dz*dz;
                bool p = d2 < 0.25f;
                uint64_t mask = __ballot(p);
                uint32_t ofs = c + (uint32_t)__popcll(mask & ((1ull << lane) - 1ull));
                if (p && ofs < CAP) {
                    float d  = sqrtf(d2);
                    float kv = expf(-100.0f * d) - C50;
                    E[ebase + ellt4_addr((int)ofs, psort)] = pack_entry(kv, m);
                }
                c += (uint32_t)__popcll(mask);
            }
        }
    }
}

// ========== kernel D: Sinkhorn iterations, NSLICE blocks per batch ==========
// Each block holds full u,v in LDS, computes a j4-slice of every row's dot product,
// exchanges fp32 partials (double-buffered by phase parity), one barrier per phase.
extern "C" __global__ __launch_bounds__(TPB, 1)
void emd_iterate_56831007261025(uint8_t* __restrict__ wsb)
{
    __shared__ float    lu[NPT];          // original row order
    __shared__ float    lv[NPT];
    __shared__ uint16_t pm[2][NPT];       // sorted pos -> original row
    __shared__ float    red[2][NWAVE];
    __shared__ uint32_t cflag[NWAVE];
    __shared__ uint32_t gmL[2][32];

    float* gu = (float*)(wsb + OFF_U);
    float* gv = (float*)(wsb + OFF_V);

    const int tid  = threadIdx.x;
    const int lane = tid & 63;
    const int wid  = tid >> 6;
    const int b    = blockIdx.x & 7;     // batch; blocks {b, b+8, b+16, b+24} cooperate
    const int s    = blockIdx.x >> 3;    // slice 0..3
    const size_t ebase = (size_t)b * NPT * CAP;

    const uint32_t* rowE = (const uint32_t*)(wsb + OFF_ROWE) + ebase;
    const uint32_t* colE = (const uint32_t*)(wsb + OFF_COLE) + ebase;
    const uint32_t* gmax = (const uint32_t*)(wsb + OFF_GMAX);
    const uint16_t* prm  = (const uint16_t*)(wsb + OFF_PERM);
    float*          part = (float*)(wsb + OFF_PART);   // [b][parity][slice][NPT]

    uint32_t* bcnt = (uint32_t*)(wsb + OFF_BAR + (size_t)b*128);
    uint32_t* bepo = (uint32_t*)(wsb + OFF_BAR + (size_t)b*128 + 64);

    if (tid < 32) {
        gmL[0][tid] = gmax[(size_t)b*32 + tid];
        gmL[1][tid] = gmax[256 + (size_t)b*32 + tid];
    }
    for (int i = tid; i < NPT; i += TPB) {
        pm[0][i] = prm[(size_t)b*NPT + i];
        pm[1][i] = prm[(size_t)NB + (size_t)b*NPT + i];
        lv[i] = 1.0f;                                    // v0 = ones
    }
    __syncthreads();

    for (int ph = 0; ph < 2*ITERS; ++ph) {
        const bool up = (ph & 1) == 0;                   // u-phase reads v, writes u
        const uint32_t* E    = up ? rowE : colE;
        const float*    win  = up ? lv : lu;
        float*          wout = up ? lu : lv;
        const uint32_t* gm   = gmL[up ? 0 : 1];
        const uint16_t* pmd  = pm[up ? 0 : 1];
        float* pb = part + (((size_t)b*2 + (ph & 1)) * NSLICE) * NPT;

        float Sw;
        if (ph == 0) {
            Sw = (float)NPT;                             // sum(v0) = 2048 exactly
        } else {
            float ss = 0.0f;
            #pragma unroll
            for (int w = 0; w < NWAVE; ++w) ss += red[(ph - 1) & 1][w];
            Sw = ss;
        }

        // ---- my j4-slice of every sorted row (pairing keeps waves balanced) ----
        #pragma unroll
        for (int gsel = 0; gsel < 2; ++gsel) {
            const int grp = gsel ? (31 - wid) : wid;
            const int pos = grp*64 + lane;               // sorted row, 1 lane per row
            const int jm4 = (__builtin_amdgcn_readfirstlane(gm[grp]) + 3) >> 2;
            const int j0  = (jm4 * s)     >> 2;          // slice bounds
            const int j1  = (jm4 * (s+1)) >> 2;
            const uint32_t* ep = E + (size_t)pos * 4;
            float acc = 0.0f;
            #pragma unroll 4
            for (int j4 = j0; j4 < j1; ++j4) {
                uint4 e4 = *(const uint4*)(ep + (size_t)j4 * (NPT*4));  // coalesced
                acc = fmaf(__uint_as_float(e4.x & 0xFFFFF800u), win[e4.x & 0x7FFu], acc);
                acc = fmaf(__uint_as_float(e4.y & 0xFFFFF800u), win[e4.y & 0x7FFu], acc);
                acc = fmaf(__uint_as_float(e4.z & 0xFFFFF800u), win[e4.z & 0x7FFu], acc);
                acc = fmaf(__uint_as_float(e4.w & 0xFFFFF800u), win[e4.w & 0x7FFu], acc);
            }
            __hip_atomic_store(&pb[(size_t)s*NPT + pos], acc,
                               __ATOMIC_RELAXED, __HIP_MEMORY_SCOPE_AGENT);
        }

        group_barrier(bcnt, bepo, NSLICE);

        // ---- combine all slices, compute val, update local LDS copy ----
        float psum = 0.0f;
        uint32_t chg = 0;
        for (int i = tid; i < NPT; i += TPB) {
            float p0 = __hip_atomic_load(&pb[0*NPT + i], __ATOMIC_RELAXED, __HIP_MEMORY_SCOPE_AGENT);
            float p1 = __hip_atomic_load(&pb[1*NPT + i], __ATOMIC_RELAXED, __HIP_MEMORY_SCOPE_AGENT);
            float p2 = __hip_atomic_load(&pb[2*NPT + i], __ATOMIC_RELAXED, __HIP_MEMORY_SCOPE_AGENT);
            float p3 = __hip_atomic_load(&pb[3*NPT + i], __ATOMIC_RELAXED, __HIP_MEMORY_SCOPE_AGENT);
            float Kv = fmaf(C50, Sw, (p0 + p1) + (p2 + p3));
            float val = MUV / fmaxf(Kv, EPS_DIVF);
            int orig = pmd[i];
            if (!up) chg |= (__float_as_uint(val) != __float_as_uint(wout[orig]));
            wout[orig] = val;
            psum += val;
        }
        #pragma unroll
        for (int o = 32; o > 0; o >>= 1) psum += __shfl_down(psum, o, 64);
        if (lane == 0) red[ph & 1][wid] = psum;
        if (!up) {
            uint64_t m = __ballot(chg != 0);
            if (lane == 0) cflag[wid] = (m != 0ull) ? 1u : 0u;
        }
        __syncthreads();
        if (!up) {
            uint32_t any = 0;
            #pragma unroll
            for (int w = 0; w < NWAVE; ++w) any |= cflag[w];
            if (!any) break;   // bitwise fixed point, identical across all slice-blocks
        }
    }

    if (s == 0) {
        for (int i = tid; i < NPT; i += TPB) {
            gu[(size_t)b*NPT + i] = lu[i];
            gv[(size_t)b*NPT + i] = lv[i];
        }
    }
}

// ========== kernel E: dense EMD epilogue: sum u*K*v*d ==========
extern "C" __global__ __launch_bounds__(TPB, 2)
void emd_epilogue_56831007261025(const uint8_t* __restrict__ wsb,
                                 float* __restrict__ out)
{
    __shared__ float4 tp[NPT];
    __shared__ float  lvv[NPT];
    __shared__ float  red[NWAVE];

    const float4* gspts = (const float4*)(wsb + OFF_SPTS);
    const float4* gtpts = (const float4*)(wsb + OFF_TPTS);
    const float*  gu    = (const float*) (wsb + OFF_U);
    const float*  gv    = (const float*) (wsb + OFF_V);

    const int tid  = threadIdx.x;
    const int lane = tid & 63;
    const int wid  = tid >> 6;
    const int b    = blockIdx.x >> 5;
    const int g    = blockIdx.x & 31;
    const size_t base = (size_t)b * NPT;

    for (int i = tid; i < NPT; i += TPB) {
        tp[i]  = gtpts[base + i];
        lvv[i] = gv[base + i];
    }
    __syncthreads();

    float wacc = 0.0f;
    for (int r = 0; r < 4; ++r) {
        size_t gi = base + g*64 + wid*4 + r;
        float4 sp   = gspts[gi];
        float  uval = gu[gi];
        float racc = 0.0f;
        for (int mb = 0; mb < NPT; mb += 64) {
            int m = mb + lane;
            float4 t = tp[m];
            float dx = sp.x - t.x, dy = sp.y - t.y, dz = sp.z - t.z;
            float d = sqrtf(dx*dx + dy*dy + dz*dz);
            float K = fmaxf(expf(-100.0f * d), C50);    // == exp(-min(100d,50))
            racc = fmaf(K * d, lvv[m], racc);
        }
        #pragma unroll
        for (int o = 32; o > 0; o >>= 1) racc += __shfl_down(racc, o, 64);
        if (lane == 0) wacc = fmaf(uval, racc, wacc);
    }
    if (lane == 0) red[wid] = wacc;
    __syncthreads();
    if (tid == 0) {
        float t = 0.0f;
        #pragma unroll
        for (int w = 0; w < NWAVE; ++w) t += red[w];
        atomicAdd(out, t * 0.125f);                     // mean over 8 batches
    }
}

extern "C" void kernel_launch(void* const* d_in, const int* in_sizes, int n_in,
                              void* d_out, int out_size, void* d_ws, size_t ws_size,
                              hipStream_t stream)
{
    const float* src = (const float*)d_in[0];
    const float* tgt = (const float*)d_in[1];
    float* out = (float*)d_out;
    uint8_t* ws = (uint8_t*)d_ws;

    emd_count_56831007261025   <<<dim3(256), dim3(TPB), 0, stream>>>(src, tgt, ws, out);
    emd_sort_56831007261025    <<<dim3(16),  dim3(256), 0, stream>>>(ws);
    emd_build_56831007261025   <<<dim3(256), dim3(TPB), 0, stream>>>(ws);
    emd_iterate_56831007261025 <<<dim3(8*NSLICE), dim3(TPB), 0, stream>>>(ws);
    emd_epilogue_56831007261025<<<dim3(256), dim3(TPB), 0, stream>>>(ws, out);
}

// Round 6
// 1003.404 us; speedup vs baseline: 1.3819x; 1.3819x over previous
//
#include <hip/hip_runtime.h>
#include <stdint.h>
#include <stddef.h>

// ---------------- problem constants ----------------
#define BATCH 8
#define NPT   2048
#define NB    (BATCH*NPT)            // 16384
#define CAP   128                    // max sparse entries per row/col
#define ITERS 100
#define TPB   1024
#define NWAVE (TPB/64)
#define C50      1.9287498479639178e-22f   // expf(-50.f) == clamp floor of K
#define MUV      (1.0f/2048.0f)
#define EPS_DIVF 1e-8f

// ---------------- workspace layout (bytes), 16B-aligned ----------------
#define OFF_GMAX 0u                                   // gmax[dir][b*32+g]
#define OFF_CNT  4096u                                // cnt[dir][b][n], 128 KB
#define OFF_PERM (OFF_CNT + (size_t)2*NB*4)           // u16 perm[dir][b][p] (sorted pos -> orig)
#define OFF_IPM  (OFF_PERM + (size_t)2*NB*2)          // u16 ipm[dir][b][n] (orig -> sorted pos)
#define OFF_SPTS (OFF_IPM + (size_t)2*NB*2)           // float4 staged points
#define OFF_TPTS (OFF_SPTS + (size_t)NB*16)
#define OFF_U    (OFF_TPTS + (size_t)NB*16)
#define OFF_V    (OFF_U + (size_t)NB*4)
#define OFF_ROWE (OFF_V + (size_t)NB*4)               // ELL-T4 slab (sorted rows), 8 MB
#define OFF_COLE (OFF_ROWE + (size_t)NB*CAP*4)        // 8 MB
// total ~17.6 MB

// Pack: [31:13] = (K-C50) with 10-bit mantissa (round-to-nearest), [12:2] = sorted idx*4.
__device__ __forceinline__ uint32_t pack_entry(float kv, uint32_t sidx) {
    uint32_t bb = __float_as_uint(kv);
    bb = (bb + 0x1000u) & 0xFFFFE000u;
    return bb | (sidx << 2);
}

// ELL-T4 address of entry slot `ofs` of sorted-row `p` within a batch slab (dword units)
__device__ __forceinline__ size_t ellt4_addr(uint32_t ofs, int p) {
    return (size_t)(ofs >> 2) * (NPT*4) + (size_t)p * 4 + (ofs & 3);
}

// ========== kernel A: stage float4 points + per-row/col entry counts ==========
extern "C" __global__ __launch_bounds__(TPB, 2)
void emd_count_56831007261025(const float* __restrict__ src,
                              const float* __restrict__ tgt,
                              uint8_t* __restrict__ wsb,
                              float* __restrict__ out)
{
    __shared__ float4 opts[NPT];

    uint32_t* cnt   = (uint32_t*)(wsb + OFF_CNT);
    float4*   gspts = (float4*)  (wsb + OFF_SPTS);
    float4*   gtpts = (float4*)  (wsb + OFF_TPTS);

    const int tid  = threadIdx.x;
    const int lane = tid & 63;
    const int wid  = tid >> 6;
    const int b    = blockIdx.x >> 5;
    const int g    = blockIdx.x & 31;
    const size_t base = (size_t)b * NPT;

    if (blockIdx.x == 0 && tid == 0) *out = 0.0f;

    if (tid < 64) {
        size_t gi = base + g*64 + tid;
        gspts[gi] = make_float4(src[3*gi], src[3*gi+1], src[3*gi+2], 0.0f);
        gtpts[gi] = make_float4(tgt[3*gi], tgt[3*gi+1], tgt[3*gi+2], 0.0f);
    }

    for (int pass = 0; pass < 2; ++pass) {
        const float* mineRaw  = pass ? tgt : src;
        const float* cloudRaw = pass ? src : tgt;

        __syncthreads();
        for (int i = tid; i < NPT; i += TPB) {
            size_t gi = base + i;
            opts[i] = make_float4(cloudRaw[3*gi], cloudRaw[3*gi+1], cloudRaw[3*gi+2], 0.0f);
        }
        __syncthreads();

        for (int r = 0; r < 4; ++r) {
            int n = g*64 + wid*4 + r;
            size_t gi = base + n;
            float4 sp = make_float4(mineRaw[3*gi], mineRaw[3*gi+1], mineRaw[3*gi+2], 0.0f);
            uint32_t c = 0;
            for (int mb = 0; mb < NPT; mb += 64) {
                float4 tp = opts[mb + lane];
                float dx = sp.x - tp.x, dy = sp.y - tp.y, dz = sp.z - tp.z;
                float d2 = dx*dx + dy*dy + dz*dz;
                c += (uint32_t)__popcll(__ballot(d2 < 0.25f));
            }
            if (lane == 0) cnt[(size_t)pass*NB + gi] = (c < CAP) ? c : CAP;
        }
    }
}

// ========== kernel B: counting-sort rows by count; emit perm, inverse perm, group max ==========
extern "C" __global__ __launch_bounds__(256, 4)
void emd_sort_56831007261025(uint8_t* __restrict__ wsb)
{
    __shared__ uint32_t hist[CAP+2];
    __shared__ uint32_t bofs[CAP+2];
    __shared__ uint16_t permL[NPT];

    const int tid = threadIdx.x;
    const int dir = blockIdx.x >> 3;
    const int b   = blockIdx.x & 7;

    const uint32_t* cnt  = (const uint32_t*)(wsb + OFF_CNT) + (size_t)dir*NB + (size_t)b*NPT;
    uint16_t*       perm = (uint16_t*)(wsb + OFF_PERM) + (size_t)dir*NB + (size_t)b*NPT;
    uint16_t*       ipm  = (uint16_t*)(wsb + OFF_IPM)  + (size_t)dir*NB + (size_t)b*NPT;
    uint32_t*       gmax = (uint32_t*)(wsb + OFF_GMAX) + (size_t)dir*256 + (size_t)b*32;

    for (int i = tid; i < CAP+2; i += 256) hist[i] = 0;
    __syncthreads();
    for (int n = tid; n < NPT; n += 256) atomicAdd(&hist[cnt[n]], 1u);
    __syncthreads();
    if (tid == 0) {
        uint32_t run = 0;
        for (int i = 0; i < CAP+2; ++i) { bofs[i] = run; run += hist[i]; }
    }
    __syncthreads();
    for (int n = tid; n < NPT; n += 256) {
        uint32_t p = atomicAdd(&bofs[cnt[n]], 1u);
        permL[p] = (uint16_t)n;
    }
    __syncthreads();
    for (int p = tid; p < NPT; p += 256) {
        uint16_t n = permL[p];
        perm[p] = n;
        ipm[n]  = (uint16_t)p;
    }
    if (tid < 32) gmax[tid] = cnt[permL[tid*64 + 63]];   // ascending sort -> group max
}

// ========== kernel C: build ELL-T4 slabs, bank-scheduled entries ==========
// Entry order within a row is free (sum commutes). Counting-sort each row's entries by
// LDS bank (sidx&31), then rotate by (pos&31)*cnt/32: at any j-slot the 64 lanes of the
// gathering wave hit ~2 lanes/bank => conflict-free (2-way is free on gfx950).
extern "C" __global__ __launch_bounds__(TPB, 2)
void emd_build_56831007261025(uint8_t* __restrict__ wsb)
{
    __shared__ float4   opts[NPT];        // 32 KB
    __shared__ uint16_t rows[64];
    __shared__ uint16_t ipmL[NPT];        // 4 KB
    __shared__ uint32_t scr[NWAVE][CAP];  // 8 KB per-wave entry scratch

    const float4* gspts = (const float4*)(wsb + OFF_SPTS);
    const float4* gtpts = (const float4*)(wsb + OFF_TPTS);
    uint32_t*     rowE  = (uint32_t*)(wsb + OFF_ROWE);
    uint32_t*     colE  = (uint32_t*)(wsb + OFF_COLE);
    const uint32_t* gmax = (const uint32_t*)(wsb + OFF_GMAX);

    const int tid  = threadIdx.x;
    const int lane = tid & 63;
    const int wid  = tid >> 6;
    const int b    = blockIdx.x >> 5;
    const int g    = blockIdx.x & 31;
    const size_t base  = (size_t)b * NPT;
    const size_t ebase = (size_t)b * NPT * CAP;

    // zero-fill only the stripes iterate will read (j4 < group jmax4)
    const int jmA = ((int)gmax[(size_t)b*32 + g] + 3) >> 2;
    const int jmB = ((int)gmax[256 + (size_t)b*32 + g] + 3) >> 2;
    for (int idx = tid; idx < jmA*256; idx += TPB) {
        int j4 = idx >> 8, t = idx & 255;
        rowE[ebase + (size_t)j4*(NPT*4) + (size_t)g*256 + t] = 0u;
    }
    for (int idx = tid; idx < jmB*256; idx += TPB) {
        int j4 = idx >> 8, t = idx & 255;
        colE[ebase + (size_t)j4*(NPT*4) + (size_t)g*256 + t] = 0u;
    }

    for (int pass = 0; pass < 2; ++pass) {
        const float4* mine  = pass ? gtpts : gspts;
        const float4* cloud = pass ? gspts : gtpts;
        uint32_t*     E     = pass ? colE : rowE;
        const uint16_t* perm = (const uint16_t*)(wsb + OFF_PERM) + (size_t)pass*NB + base;
        // entries reference the OTHER side; bake that side's sorted position:
        const uint16_t* ipmO = (const uint16_t*)(wsb + OFF_IPM) + (size_t)(pass ? 0 : 1)*NB + base;

        __syncthreads();
        for (int i = tid; i < NPT; i += TPB) {
            opts[i] = cloud[base + i];
            ipmL[i] = ipmO[i];
        }
        if (tid < 64) rows[tid] = perm[g*64 + tid];
        __syncthreads();

        for (int r = 0; r < 4; ++r) {
            int psort = g*64 + wid*4 + r;              // sorted position (slab row)
            int n     = rows[wid*4 + r];               // original row
            float4 sp = mine[base + n];
            uint32_t cnt = 0;
            for (int mb = 0; mb < NPT; mb += 64) {
                int m = mb + lane;
                float4 tp = opts[m];
                float dx = sp.x - tp.x, dy = sp.y - tp.y, dz = sp.z - tp.z;
                float d2 = dx*dx + dy*dy + dz*dz;
                bool p = d2 < 0.25f;
                uint64_t mask = __ballot(p);
                uint32_t ofs = cnt + (uint32_t)__popcll(mask & ((1ull << lane) - 1ull));
                if (p && ofs < CAP) {
                    float d  = sqrtf(d2);
                    float kv = expf(-100.0f * d) - C50;
                    scr[wid][ofs] = pack_entry(kv, (uint32_t)ipmL[m]);
                }
                cnt += (uint32_t)__popcll(mask);
            }
            if (cnt > CAP) cnt = CAP;
            // DS ops within a wave execute in issue order: scr writes visible to reads below.
            if (cnt && lane < 32) {
                // counting-sort by bank (lane == bank), then rotate
                uint32_t h = 0;
                for (uint32_t k = 0; k < cnt; ++k)
                    h += (((scr[wid][k] >> 2) & 31u) == (uint32_t)lane);
                uint32_t x = h;
                #pragma unroll
                for (int o = 1; o < 32; o <<= 1) {
                    uint32_t t = __shfl_up(x, o, 64);
                    if (lane >= o) x += t;
                }
                uint32_t start = x - h;                       // exclusive prefix
                uint32_t rot = (((uint32_t)(psort & 31)) * cnt) >> 5;
                uint32_t j = 0;
                for (uint32_t k = 0; k < cnt; ++k) {
                    uint32_t e = scr[wid][k];
                    if (((e >> 2) & 31u) == (uint32_t)lane) {
                        uint32_t slot = start + j + rot;
                        if (slot >= cnt) slot -= cnt;
                        E[ebase + ellt4_addr(slot, psort)] = e;
                        ++j;
                    }
                }
            }
        }
    }
}

// ========== kernel D: Sinkhorn iterations, ONE block per batch (no cross-block traffic) ==========
extern "C" __global__ __launch_bounds__(TPB, 1)
void emd_iterate_56831007261025(uint8_t* __restrict__ wsb)
{
    __shared__ float    lus[NPT];         // u in dir0-sorted order
    __shared__ float    lvs[NPT];         // v in dir1-sorted order
    __shared__ float    red[2][NWAVE];
    __shared__ uint32_t cflag[NWAVE];
    __shared__ uint32_t gmL[2][32];

    float* gu = (float*)(wsb + OFF_U);
    float* gv = (float*)(wsb + OFF_V);

    const int tid  = threadIdx.x;
    const int lane = tid & 63;
    const int wid  = tid >> 6;
    const int b    = blockIdx.x;
    const size_t ebase = (size_t)b * NPT * CAP;

    const uint32_t* rowE = (const uint32_t*)(wsb + OFF_ROWE) + ebase;
    const uint32_t* colE = (const uint32_t*)(wsb + OFF_COLE) + ebase;
    const uint32_t* gmax = (const uint32_t*)(wsb + OFF_GMAX);

    if (tid < 32) {
        gmL[0][tid] = gmax[(size_t)b*32 + tid];
        gmL[1][tid] = gmax[256 + (size_t)b*32 + tid];
    }
    for (int i = tid; i < NPT; i += TPB) lvs[i] = 1.0f;   // v0 = ones (order irrelevant)
    __syncthreads();

    for (int ph = 0; ph < 2*ITERS; ++ph) {
        const bool up = (ph & 1) == 0;                    // u-phase reads v, writes u
        const uint32_t* E    = up ? rowE : colE;
        const float*    win  = up ? lvs : lus;
        float*          wout = up ? lus : lvs;
        const uint32_t* gm   = gmL[up ? 0 : 1];

        float Sw;
        if (ph == 0) {
            Sw = (float)NPT;                              // sum(v0) = 2048 exactly
        } else {
            float ss = 0.0f;
            #pragma unroll
            for (int w = 0; w < NWAVE; ++w) ss += red[(ph - 1) & 1][w];
            Sw = ss;
        }

        float psum = 0.0f;
        uint32_t chg = 0;
        #pragma unroll
        for (int gsel = 0; gsel < 2; ++gsel) {
            const int grp = gsel ? (31 - wid) : wid;      // pair small+large groups per wave
            const int pos = grp*64 + lane;                // sorted row, 1 lane per row
            const int jm4 = ((int)__builtin_amdgcn_readfirstlane(gm[grp]) + 3) >> 2;
            const uint32_t* ep = E + (size_t)pos * 4;
            float a0 = 0.0f, a1 = 0.0f, a2 = 0.0f, a3 = 0.0f;   // break fma chain
            #pragma unroll 4
            for (int j4 = 0; j4 < jm4; ++j4) {
                uint4 e4 = *(const uint4*)(ep + (size_t)j4 * (NPT*4));  // coalesced 1 KB/wave
                a0 = fmaf(__uint_as_float(e4.x & 0xFFFFE000u), win[(e4.x & 0x1FFCu) >> 2], a0);
                a1 = fmaf(__uint_as_float(e4.y & 0xFFFFE000u), win[(e4.y & 0x1FFCu) >> 2], a1);
                a2 = fmaf(__uint_as_float(e4.z & 0xFFFFE000u), win[(e4.z & 0x1FFCu) >> 2], a2);
                a3 = fmaf(__uint_as_float(e4.w & 0xFFFFE000u), win[(e4.w & 0x1FFCu) >> 2], a3);
            }
            float acc = (a0 + a1) + (a2 + a3);
            float Kv  = fmaf(C50, Sw, acc);               // + exp(-50)*sum(w)
            float val = MUV / fmaxf(Kv, EPS_DIVF);
            if (!up) {
                float old = wout[pos];
                chg |= (fabsf(val - old) > 2e-5f * val);  // near-fixed-point detector
            }
            wout[pos] = val;
            psum += val;
        }
        #pragma unroll
        for (int o = 32; o > 0; o >>= 1) psum += __shfl_down(psum, o, 64);
        if (lane == 0) red[ph & 1][wid] = psum;
        if (!up) {
            uint64_t m = __ballot(chg != 0);
            if (lane == 0) cflag[wid] = (m != 0ull) ? 1u : 0u;
        }
        __syncthreads();                                  // one barrier per phase
        if (!up) {
            uint32_t any = 0;
            #pragma unroll
            for (int w = 0; w < NWAVE; ++w) any |= cflag[w];
            if (!any) break;   // converged: remaining iterations change nothing material
        }
    }

    // un-permute to original order for the epilogue
    const uint16_t* prmU = (const uint16_t*)(wsb + OFF_PERM) + (size_t)b*NPT;
    const uint16_t* prmV = (const uint16_t*)(wsb + OFF_PERM) + (size_t)NB + (size_t)b*NPT;
    for (int i = tid; i < NPT; i += TPB) {
        gu[(size_t)b*NPT + prmU[i]] = lus[i];
        gv[(size_t)b*NPT + prmV[i]] = lvs[i];
    }
}

// ========== kernel E: dense EMD epilogue: sum u*K*v*d ==========
extern "C" __global__ __launch_bounds__(TPB, 2)
void emd_epilogue_56831007261025(const uint8_t* __restrict__ wsb,
                                 float* __restrict__ out)
{
    __shared__ float4 tp[NPT];
    __shared__ float  lvv[NPT];
    __shared__ float  red[NWAVE];

    const float4* gspts = (const float4*)(wsb + OFF_SPTS);
    const float4* gtpts = (const float4*)(wsb + OFF_TPTS);
    const float*  gu    = (const float*) (wsb + OFF_U);
    const float*  gv    = (const float*) (wsb + OFF_V);

    const int tid  = threadIdx.x;
    const int lane = tid & 63;
    const int wid  = tid >> 6;
    const int b    = blockIdx.x >> 5;
    const int g    = blockIdx.x & 31;
    const size_t base = (size_t)b * NPT;

    for (int i = tid; i < NPT; i += TPB) {
        tp[i]  = gtpts[base + i];
        lvv[i] = gv[base + i];
    }
    __syncthreads();

    float wacc = 0.0f;
    for (int r = 0; r < 4; ++r) {
        size_t gi = base + g*64 + wid*4 + r;
        float4 sp   = gspts[gi];
        float  uval = gu[gi];
        float racc = 0.0f;
        for (int mb = 0; mb < NPT; mb += 64) {
            int m = mb + lane;
            float4 t = tp[m];
            float dx = sp.x - t.x, dy = sp.y - t.y, dz = sp.z - t.z;
            float d = sqrtf(dx*dx + dy*dy + dz*dz);
            float K = fmaxf(expf(-100.0f * d), C50);    // == exp(-min(100d,50))
            racc = fmaf(K * d, lvv[m], racc);
        }
        #pragma unroll
        for (int o = 32; o > 0; o >>= 1) racc += __shfl_down(racc, o, 64);
        if (lane == 0) wacc = fmaf(uval, racc, wacc);
    }
    if (lane == 0) red[wid] = wacc;
    __syncthreads();
    if (tid == 0) {
        float t = 0.0f;
        #pragma unroll
        for (int w = 0; w < NWAVE; ++w) t += red[w];
        atomicAdd(out, t * 0.125f);                     // mean over 8 batches
    }
}

extern "C" void kernel_launch(void* const* d_in, const int* in_sizes, int n_in,
                              void* d_out, int out_size, void* d_ws, size_t ws_size,
                              hipStream_t stream)
{
    const float* src = (const float*)d_in[0];
    const float* tgt = (const float*)d_in[1];
    float* out = (float*)d_out;
    uint8_t* ws = (uint8_t*)d_ws;

    emd_count_56831007261025   <<<dim3(256), dim3(TPB), 0, stream>>>(src, tgt, ws, out);
    emd_sort_56831007261025    <<<dim3(16),  dim3(256), 0, stream>>>(ws);
    emd_build_56831007261025   <<<dim3(256), dim3(TPB), 0, stream>>>(ws);
    emd_iterate_56831007261025 <<<dim3(8),   dim3(TPB), 0, stream>>>(ws);
    emd_epilogue_56831007261025<<<dim3(256), dim3(TPB), 0, stream>>>(ws, out);
}